// Round 12
// baseline (431.859 us; speedup 1.0000x reference)
//
#include <hip/hip_runtime.h>
#include <hip/hip_bf16.h>

#define DIV_UP(a,b) (((a)+(b)-1)/(b))

typedef __attribute__((ext_vector_type(8))) short short8;
typedef __attribute__((ext_vector_type(4))) float floatx4;
typedef _Float16 half8v __attribute__((ext_vector_type(8)));

// ---------- bf16 helpers (manual, deterministic RNE) ----------
static __device__ __forceinline__ unsigned short f2bf(float v) {
    unsigned u = __builtin_bit_cast(unsigned, v);
    u += 0x7fffu + ((u >> 16) & 1u);
    return (unsigned short)(u >> 16);
}
static __device__ __forceinline__ float bflo(unsigned v) {
    return __builtin_bit_cast(float, v << 16);
}
static __device__ __forceinline__ float bfhi(unsigned v) {
    return __builtin_bit_cast(float, v & 0xffff0000u);
}

template <int CPL>
static __device__ __forceinline__ void load_bf16v(const unsigned short* p, float* d) {
    if constexpr (CPL == 8) {
        uint4 v = *(const uint4*)p;
        d[0] = bflo(v.x); d[1] = bfhi(v.x);
        d[2] = bflo(v.y); d[3] = bfhi(v.y);
        d[4] = bflo(v.z); d[5] = bfhi(v.z);
        d[6] = bflo(v.w); d[7] = bfhi(v.w);
    } else if constexpr (CPL == 4) {
        uint2 v = *(const uint2*)p;
        d[0] = bflo(v.x); d[1] = bfhi(v.x);
        d[2] = bflo(v.y); d[3] = bfhi(v.y);
    } else if constexpr (CPL == 2) {
        unsigned v = *(const unsigned*)p;
        d[0] = bflo(v); d[1] = bfhi(v);
    } else {
        d[0] = bflo(*p);
    }
}

template <int CPL>
static __device__ __forceinline__ void store_bf16v(unsigned short* p, const float* s) {
    unsigned short tmp[CPL];
#pragma unroll
    for (int c = 0; c < CPL; ++c) tmp[c] = f2bf(s[c]);
    if constexpr (CPL == 8) *(uint4*)p = *(uint4*)tmp;
    else if constexpr (CPL == 4) *(ushort4*)p = *(ushort4*)tmp;
    else if constexpr (CPL == 2) *(ushort2*)p = *(ushort2*)tmp;
    else p[0] = tmp[0];
}

// ---------- DPP group reduction (VALU pipe, not DS) ----------
template <int CTRL>
static __device__ __forceinline__ float dpp_mv(float x) {
    int r = __builtin_amdgcn_update_dpp(0, __builtin_bit_cast(int, x), CTRL, 0xF, 0xF, false);
    return __builtin_bit_cast(float, r);
}
template <int G>
static __device__ __forceinline__ float group_reduce(float x) {
    x += dpp_mv<0xB1>(x);   // xor 1
    x += dpp_mv<0x4E>(x);   // xor 2 -> quad sums
    if constexpr (G == 8) {
        x += __shfl_xor(x, 4, 64);
    } else if constexpr (G >= 16) {
        x += dpp_mv<0x124>(x);  // row_ror:4
        x += dpp_mv<0x128>(x);  // row_ror:8 -> 16-lane sum
        if constexpr (G >= 32) x += __shfl_xor(x, 16, 64);
        if constexpr (G >= 64) x += __shfl_xor(x, 32, 64);
    }
    return x;
}

// ---------- merged weight prep: 3 transposed pairs + x->bf16 ----------
static __device__ __forceinline__ void tr_pair(const float* Wa, const float* Wb, int K, int Nn,
                                               unsigned short* Wt, int i) {
    int tot = K * Nn;
    const float* W = (i < tot) ? Wa : Wb;
    unsigned short* dst = Wt + ((i < tot) ? 0 : (size_t)Nn * K);
    int ii = (i < tot) ? i : i - tot;
    int k = ii % K, n = ii / K;
    dst[(size_t)n * K + k] = f2bf(W[(size_t)k * Nn + n]);
}

__global__ void prep_all(const float* __restrict__ x,
                         const float* __restrict__ Wl1, const float* __restrict__ Wr1,
                         const float* __restrict__ Wl2, const float* __restrict__ Wr2,
                         const float* __restrict__ Wlp, const float* __restrict__ Wrp,
                         unsigned short* __restrict__ xbf,
                         unsigned short* __restrict__ wt1, unsigned short* __restrict__ wt2,
                         unsigned short* __restrict__ wt3, int N) {
    const int S1 = 2 * 64 * 1024, S2 = 2 * 1024 * 256, S3 = 2 * 256 * 384;
    int id = blockIdx.x * blockDim.x + threadIdx.x;
    if (id < S1) tr_pair(Wl1, Wr1, 64, 1024, wt1, id);
    else if (id < S1 + S2) tr_pair(Wl2, Wr2, 1024, 256, wt2, id - S1);
    else if (id < S1 + S2 + S3) tr_pair(Wlp, Wrp, 256, 384, wt3, id - S1 - S2);
    else {
        int i = id - S1 - S2 - S3;
        if (i < N * 64) xbf[i] = f2bf(x[i]);
    }
}

// ---------- MFMA bf16 GEMM: C[M,Ntot] = A[M,K] @ Bt[Ntot,K]^T ----------
__global__ __launch_bounds__(256) void gemm_mfma(
    const unsigned short* __restrict__ A, const unsigned short* __restrict__ Bt,
    unsigned short* __restrict__ C, int M, int Ntot, int K) {
    constexpr int LDA = 40;
    __shared__ unsigned short As[128 * LDA];
    __shared__ unsigned short Bs[128 * LDA];
    const int tid = threadIdx.x;
    const int m0 = blockIdx.y * 128, n0 = blockIdx.x * 128;
    const int wave = tid >> 6, lane = tid & 63;
    const int wm = (wave >> 1) * 64, wn = (wave & 1) * 64;
    const int r15 = lane & 15, quad = lane >> 4;
    const int sr = tid >> 1, skc = tid & 1;
    floatx4 acc[4][4];
#pragma unroll
    for (int i = 0; i < 4; ++i)
#pragma unroll
        for (int j = 0; j < 4; ++j) acc[i][j] = (floatx4)0.f;

    for (int k0 = 0; k0 < K; k0 += 32) {
        uint4 a0 = make_uint4(0, 0, 0, 0), a1 = make_uint4(0, 0, 0, 0);
        int am = m0 + sr;
        if (am < M) {
            const unsigned short* ap = A + (size_t)am * K + k0 + skc * 16;
            a0 = *(const uint4*)ap;
            a1 = *(const uint4*)(ap + 8);
        }
        const unsigned short* bp = Bt + (size_t)(n0 + sr) * K + k0 + skc * 16;
        uint4 b0 = *(const uint4*)bp;
        uint4 b1 = *(const uint4*)(bp + 8);
        *(uint4*)(&As[sr * LDA + skc * 16]) = a0;
        *(uint4*)(&As[sr * LDA + skc * 16 + 8]) = a1;
        *(uint4*)(&Bs[sr * LDA + skc * 16]) = b0;
        *(uint4*)(&Bs[sr * LDA + skc * 16 + 8]) = b1;
        __syncthreads();
        short8 af[4], bfr[4];
#pragma unroll
        for (int i = 0; i < 4; ++i)
            af[i] = *(const short8*)(&As[(wm + i * 16 + r15) * LDA + quad * 8]);
#pragma unroll
        for (int j = 0; j < 4; ++j)
            bfr[j] = *(const short8*)(&Bs[(wn + j * 16 + r15) * LDA + quad * 8]);
#pragma unroll
        for (int i = 0; i < 4; ++i)
#pragma unroll
            for (int j = 0; j < 4; ++j)
                acc[i][j] = __builtin_amdgcn_mfma_f32_16x16x32_bf16(af[i], bfr[j], acc[i][j], 0, 0, 0);
        __syncthreads();
    }
#pragma unroll
    for (int i = 0; i < 4; ++i)
#pragma unroll
        for (int j = 0; j < 4; ++j)
#pragma unroll
            for (int r = 0; r < 4; ++r) {
                int m = m0 + wm + i * 16 + quad * 4 + r;
                int n = n0 + wn + j * 16 + r15;
                if (m < M) C[(size_t)m * Ntot + n] = f2bf(acc[i][j][r]);
            }
}

// ---------- CSR build for BOTH graphs ----------
__global__ void count2_kernel(const int* __restrict__ dst0, const int* __restrict__ dst1,
                              int E, int N, int* __restrict__ cnt) {
    int e = blockIdx.x * blockDim.x + threadIdx.x;
    if (e < E) atomicAdd(&cnt[dst0[e]], 1);
    else if (e < 2 * E) atomicAdd(&cnt[N + dst1[e - E]], 1);
}

__global__ __launch_bounds__(1024) void scan_kernel(const int* __restrict__ cnt_all, int N,
                                                    int* __restrict__ off_all, int* __restrict__ cur_all) {
    const int* cnt = cnt_all + blockIdx.x * N;
    int* off = off_all + blockIdx.x * (N + 1);
    int* cur = cur_all + blockIdx.x * N;
    __shared__ int part[1024];
    int t = threadIdx.x;
    int per = (N + 1023) >> 10;
    int base = t * per;
    int s = 0;
    for (int i = 0; i < per; ++i) { int idx = base + i; if (idx < N) s += cnt[idx]; }
    part[t] = s;
    __syncthreads();
    for (int d2 = 1; d2 < 1024; d2 <<= 1) {
        int v = (t >= d2) ? part[t - d2] : 0;
        __syncthreads();
        part[t] += v;
        __syncthreads();
    }
    int pre = (t == 0) ? 0 : part[t - 1];
    for (int i = 0; i < per; ++i) {
        int idx = base + i;
        if (idx < N) { off[idx] = pre; cur[idx] = pre; pre += cnt[idx]; }
    }
    if (t == 1023) off[N] = part[1023];
}

__global__ void fill2_kernel(const int* __restrict__ src0, const int* __restrict__ dst0,
                             const int* __restrict__ src1, const int* __restrict__ dst1,
                             int E, int N, int* __restrict__ cur, int2* __restrict__ edges) {
    int e = blockIdx.x * blockDim.x + threadIdx.x;
    if (e < E) {
        int p = atomicAdd(&cur[dst0[e]], 1);
        edges[p] = make_int2(src0[e], e);
    } else if (e < 2 * E) {
        int i = e - E;
        int p = atomicAdd(&cur[N + dst1[i]], 1);
        edges[E + p] = make_int2(src1[i], i);
    }
}

// ---------- fused attention (HASE): fp16 We in LDS, NE-edge groups, scalar edge meta ----------
// We stored as fp16, packed so one ds_read_b128 (8 halves) = 8/CPL k-slices of the
// lane's CPL channels. KPR = 8/CPL (1 for CPL=8, 2 for CPL=4).
template <int D, int CPL, int G, int NE>
static __device__ __forceinline__ void hase_group(
    const unsigned short* __restrict__ xlr, const float* __restrict__ ea,
    const _Float16* wb, const float (&att_r)[CPL], const float (&xr_r)[CPL],
    const int2* ep /*uniform*/, int c0,
    float& m, float& l, float (&acc)[CPL]) {
    constexpr int KPR = 8 / CPL;
    int2 e[NE];
#pragma unroll
    for (int n = 0; n < NE; ++n) e[n] = ep[n];
    float ev[NE][8];
#pragma unroll
    for (int n = 0; n < NE; ++n) {
        float4 a = ((const float4*)(ea + (size_t)e[n].y * 8))[0];
        float4 b = ((const float4*)(ea + (size_t)e[n].y * 8))[1];
        ev[n][0] = a.x; ev[n][1] = a.y; ev[n][2] = a.z; ev[n][3] = a.w;
        ev[n][4] = b.x; ev[n][5] = b.y; ev[n][6] = b.z; ev[n][7] = b.w;
    }
    float xv[NE][CPL], z[NE][CPL];
#pragma unroll
    for (int n = 0; n < NE; ++n) {
        load_bf16v<CPL>(xlr + (size_t)e[n].x * (2 * D) + c0, xv[n]);
#pragma unroll
        for (int c = 0; c < CPL; ++c) z[n][c] = xv[n][c] + xr_r[c];
    }
#pragma unroll
    for (int r = 0; r < 8 / KPR; ++r) {
        half8v w8 = *(const half8v*)(wb + r * (KPR * 64 * CPL));
        float wf[8];
#pragma unroll
        for (int i = 0; i < 8; ++i) wf[i] = (float)w8[i];
#pragma unroll
        for (int kk = 0; kk < KPR; ++kk) {
            const int k = r * KPR + kk;
#pragma unroll
            for (int n = 0; n < NE; ++n)
#pragma unroll
                for (int c = 0; c < CPL; ++c)
                    z[n][c] = fmaf(ev[n][k], wf[kk * CPL + c], z[n][c]);
        }
    }
    float lg[NE];
#pragma unroll
    for (int n = 0; n < NE; ++n) {
        lg[n] = 0.f;
#pragma unroll
        for (int c = 0; c < CPL; ++c) {
            float a = z[n][c] > 0.f ? z[n][c] : 0.2f * z[n][c];
            lg[n] = fmaf(att_r[c], a, lg[n]);
        }
        lg[n] = group_reduce<G>(lg[n]);
    }
    float mn = m;
#pragma unroll
    for (int n = 0; n < NE; ++n) mn = fmaxf(mn, lg[n]);
    float sc = __expf(m - mn);
    float p[NE], ps = 0.f;
#pragma unroll
    for (int n = 0; n < NE; ++n) { p[n] = __expf(lg[n] - mn); ps += p[n]; }
    m = mn;
    l = fmaf(l, sc, ps);
#pragma unroll
    for (int c = 0; c < CPL; ++c) {
        float t = p[0] * xv[0][c];
#pragma unroll
        for (int n = 1; n < NE; ++n) t = fmaf(p[n], xv[n][c], t);
        acc[c] = fmaf(acc[c], sc, t);
    }
}

template <int D, int C, int CB, int WPN, bool RELU>
__global__ __launch_bounds__(256) void attn_hase(
    const unsigned short* __restrict__ xlr, const float* __restrict__ ea,
    const float* __restrict__ We, const float* __restrict__ att,
    const int2* __restrict__ edges, const int* __restrict__ off,
    const float* __restrict__ bias, unsigned short* __restrict__ outp, int N) {
    constexpr int CPL = CB / 64;      // 8 (L1) or 4 (L2)
    constexpr int HW = CB / C;
    constexpr int G = 64 / HW;
    constexpr int NPB = 4 / WPN;
    constexpr int KPR = 8 / CPL;      // k-slices per 8-half read
    __shared__ _Float16 wsh[8 * D];   // fp16 We, swizzled
    for (int f4 = threadIdx.x; f4 < 2 * D; f4 += 256) {  // 8*D floats = 2*D float4
        int k = f4 / (D / 4);
        int c = (f4 - k * (D / 4)) * 4;
        float4 wv4 = ((const float4*)We)[f4];
        int b = c / CB, cc = c - b * CB;
        int ln = cc / CPL;
        int dst = b * (8 * CB) + (k / KPR) * (KPR * CB) + ln * 8 + (k % KPR) * CPL + (cc % CPL);
        _Float16 h4[4] = {(_Float16)wv4.x, (_Float16)wv4.y, (_Float16)wv4.z, (_Float16)wv4.w};
        *(ushort4*)&wsh[dst] = *(ushort4*)h4;
    }
    __syncthreads();

    const int wid = threadIdx.x >> 6, lane = threadIdx.x & 63;
    const int wv = wid % WPN, wn = wid / WPN;
    const int c0 = wv * CB + lane * CPL;
    const _Float16* wb = wsh + wv * (8 * CB) + lane * 8;

    float att_r[CPL];
#pragma unroll
    for (int c = 0; c < CPL; ++c) att_r[c] = att[c0 + c];

    for (int node = blockIdx.x * NPB + wn; node < N; node += gridDim.x * NPB) {
        float xr_r[CPL];
        load_bf16v<CPL>(xlr + (size_t)node * (2 * D) + D + c0, xr_r);
        float m = -1e30f, l = 0.f, acc[CPL];
#pragma unroll
        for (int c = 0; c < CPL; ++c) acc[c] = 0.f;

        const int jb = __builtin_amdgcn_readfirstlane(off[node]);
        const int je = __builtin_amdgcn_readfirstlane(off[node + 1]);
        int j = jb;
        for (; j + 4 <= je; j += 4)
            hase_group<D, CPL, G, 4>(xlr, ea, wb, att_r, xr_r, edges + j, c0, m, l, acc);
        for (; j < je; ++j)
            hase_group<D, CPL, G, 1>(xlr, ea, wb, att_r, xr_r, edges + j, c0, m, l, acc);

        float inv = 1.f / (l + 1e-16f);
        float r[CPL];
#pragma unroll
        for (int c = 0; c < CPL; ++c) {
            r[c] = fmaf(acc[c], inv, bias[c0 + c]);
            if constexpr (RELU) r[c] = fmaxf(r[c], 0.f);
        }
        store_bf16v<CPL>(outp + (size_t)node * D + c0, r);
    }
}

// ---------- fused attention, no edge_attr (layer 3): scalar, NE groups ----------
template <int D, int CPL, int G, int NE>
static __device__ __forceinline__ void noe_group(
    const unsigned short* __restrict__ xlr,
    const float (&att_r)[CPL], const float (&xr_r)[CPL],
    const int2* ep /*uniform*/, int c0,
    float& m, float& l, float (&acc)[CPL]) {
    int2 e[NE];
#pragma unroll
    for (int n = 0; n < NE; ++n) e[n] = ep[n];
    float xv[NE][CPL], lg[NE];
#pragma unroll
    for (int n = 0; n < NE; ++n)
        load_bf16v<CPL>(xlr + (size_t)e[n].x * (2 * D) + c0, xv[n]);
#pragma unroll
    for (int n = 0; n < NE; ++n) {
        lg[n] = 0.f;
#pragma unroll
        for (int c = 0; c < CPL; ++c) {
            float z = xv[n][c] + xr_r[c];
            z = z > 0.f ? z : 0.2f * z;
            lg[n] = fmaf(att_r[c], z, lg[n]);
        }
        lg[n] = group_reduce<G>(lg[n]);
    }
    float mn = m;
#pragma unroll
    for (int n = 0; n < NE; ++n) mn = fmaxf(mn, lg[n]);
    float sc = __expf(m - mn);
    float p[NE], ps = 0.f;
#pragma unroll
    for (int n = 0; n < NE; ++n) { p[n] = __expf(lg[n] - mn); ps += p[n]; }
    m = mn;
    l = fmaf(l, sc, ps);
#pragma unroll
    for (int c = 0; c < CPL; ++c) {
        float t = p[0] * xv[0][c];
#pragma unroll
        for (int n = 1; n < NE; ++n) t = fmaf(p[n], xv[n][c], t);
        acc[c] = fmaf(acc[c], sc, t);
    }
}

// D=384, C=64, CPL=8: 48 active lanes, G=8, 1 wave/node, fp32 out.
template <int D, int C, int CPL, bool RELU>
__global__ __launch_bounds__(256) void attn_noe1(
    const unsigned short* __restrict__ xlr, const float* __restrict__ att,
    const int2* __restrict__ edges, const int* __restrict__ off,
    const float* __restrict__ bias, float* __restrict__ outp, int N) {
    constexpr int ACT = D / CPL;  // 48
    constexpr int G = C / CPL;    // 8
    const int wid = threadIdx.x >> 6, lane = threadIdx.x & 63;
    const int node = blockIdx.x * 4 + wid;
    if (node >= N || lane >= ACT) return;
    const int c0 = lane * CPL;

    float att_r[CPL], xr_r[CPL];
#pragma unroll
    for (int c = 0; c < CPL; ++c) att_r[c] = att[c0 + c];
    load_bf16v<CPL>(xlr + (size_t)node * (2 * D) + D + c0, xr_r);

    float m = -1e30f, l = 0.f, acc[CPL];
#pragma unroll
    for (int c = 0; c < CPL; ++c) acc[c] = 0.f;

    const int jb = __builtin_amdgcn_readfirstlane(off[node]);
    const int je = __builtin_amdgcn_readfirstlane(off[node + 1]);
    int j = jb;
    for (; j + 4 <= je; j += 4)
        noe_group<D, CPL, G, 4>(xlr, att_r, xr_r, edges + j, c0, m, l, acc);
    for (; j < je; ++j)
        noe_group<D, CPL, G, 1>(xlr, att_r, xr_r, edges + j, c0, m, l, acc);

    float inv = 1.f / (l + 1e-16f);
    float* out = outp + (size_t)node * D + c0;
    float tmp[CPL];
#pragma unroll
    for (int c = 0; c < CPL; ++c) {
        tmp[c] = fmaf(acc[c], inv, bias[c0 + c]);
        if constexpr (RELU) tmp[c] = fmaxf(tmp[c], 0.f);
    }
    *(float4*)out = make_float4(tmp[0], tmp[1], tmp[2], tmp[3]);
    *(float4*)(out + 4) = make_float4(tmp[4], tmp[5], tmp[6], tmp[7]);
}

// ---------- head: 2-layer MLP on master (last) node of each graph ----------
__global__ void mlp_kernel(const float* __restrict__ h3, const int* __restrict__ nn,
                           const float* __restrict__ Wfc1, const float* __restrict__ bfc1,
                           const float* __restrict__ Wfc2, const float* __restrict__ bfc2,
                           float* __restrict__ out, int G) {
    int g = blockIdx.x, t = threadIdx.x;  // 64 threads
    int s = 0;
    for (int k = 0; k <= g; ++k) s += nn[k];
    const float* row = h3 + (size_t)(s - 1) * 384;
    float z = bfc1[t];
    for (int k = 0; k < 384; ++k) z = fmaf(row[k], Wfc1[k * 64 + t], z);
    z = fmaxf(z, 0.f);
    float v = z * Wfc2[t];
#pragma unroll
    for (int o = 32; o; o >>= 1) v += __shfl_xor(v, o, 64);
    if (t == 0) out[g] = v + bfc2[0];
}

extern "C" void kernel_launch(void* const* d_in, const int* in_sizes, int n_in,
                              void* d_out, int out_size, void* d_ws, size_t ws_size,
                              hipStream_t stream) {
    const float* x    = (const float*)d_in[0];
    const float* ea   = (const float*)d_in[1];
    const float* Wl1  = (const float*)d_in[2];
    const float* Wr1  = (const float*)d_in[3];
    const float* We1  = (const float*)d_in[4];
    const float* att1 = (const float*)d_in[5];
    const float* b1   = (const float*)d_in[6];
    const float* Wl2  = (const float*)d_in[7];
    const float* Wr2  = (const float*)d_in[8];
    const float* We2  = (const float*)d_in[9];
    const float* att2 = (const float*)d_in[10];
    const float* b2   = (const float*)d_in[11];
    const float* Wlp  = (const float*)d_in[12];
    const float* Wrp  = (const float*)d_in[13];
    const float* attp = (const float*)d_in[14];
    const float* bp   = (const float*)d_in[15];
    const float* Wfc1 = (const float*)d_in[16];
    const float* bfc1 = (const float*)d_in[17];
    const float* Wfc2 = (const float*)d_in[18];
    const float* bfc2 = (const float*)d_in[19];
    const int* ei     = (const int*)d_in[20];
    const int* eim    = (const int*)d_in[21];
    const int* nn     = (const int*)d_in[22];

    const int N = in_sizes[0] / 64;   // 20000
    const int E = in_sizes[20] / 2;   // 160000
    const int G = in_sizes[22];       // 100
    const int* src1 = ei,  *dst1 = ei + E;
    const int* srcm = eim, *dstm = eim + E;

    // ---- workspace layout (~160 MB peak) ----
    char* w = (char*)d_ws;
    size_t o = 0;
    auto alloc = [&](size_t b) { size_t r = o; o += (b + 255) & ~(size_t)255; return r; };
    char* R1 = w + alloc((size_t)N * 2048 * 2);
    unsigned short* xlr1 = (unsigned short*)R1;
    unsigned short* xlr3 = (unsigned short*)R1;
    float* h3 = (float*)(R1 + (size_t)N * 768 * 2 + 256);
    unsigned short* h1   = (unsigned short*)(w + alloc((size_t)N * 1024 * 2));
    unsigned short* xlr2 = (unsigned short*)(w + alloc((size_t)N * 512 * 2));
    unsigned short* h2   = (unsigned short*)(w + alloc((size_t)N * 256 * 2));
    unsigned short* xbf  = (unsigned short*)(w + alloc((size_t)N * 64 * 2));
    unsigned short* wt1  = (unsigned short*)(w + alloc((size_t)2048 * 64 * 2));
    unsigned short* wt2  = (unsigned short*)(w + alloc((size_t)512 * 1024 * 2));
    unsigned short* wt3  = (unsigned short*)(w + alloc((size_t)768 * 256 * 2));
    int*  cnt   = (int*)(w + alloc((size_t)2 * N * 4));
    int*  off   = (int*)(w + alloc((size_t)2 * (N + 1) * 4));
    int*  cur   = (int*)(w + alloc((size_t)2 * N * 4));
    int2* edges = (int2*)(w + alloc((size_t)2 * E * 8 + 4096));
    (void)ws_size; (void)n_in; (void)out_size;

    dim3 blk(256);

    // ---- weight prep (single merged launch) ----
    {
        int tot = 2 * 64 * 1024 + 2 * 1024 * 256 + 2 * 256 * 384 + N * 64;
        prep_all<<<DIV_UP(tot, 256), blk, 0, stream>>>(x, Wl1, Wr1, Wl2, Wr2, Wlp, Wrp,
                                                       xbf, wt1, wt2, wt3, N);
    }

    // ---- CSR for both graphs ----
    hipMemsetAsync(cnt, 0, (size_t)2 * N * 4, stream);
    count2_kernel<<<DIV_UP(2 * E, 256), blk, 0, stream>>>(dst1, dstm, E, N, cnt);
    scan_kernel<<<2, 1024, 0, stream>>>(cnt, N, off, cur);
    fill2_kernel<<<DIV_UP(2 * E, 256), blk, 0, stream>>>(src1, dst1, srcm, dstm, E, N, cur, edges);
    const int* off3 = off + (N + 1);
    int2* edges3 = edges + E;

    // ---- Layer 1: H=4, C=256, D=1024 — 2 waves/node, CPL=8, G=32, NE=4, fp16 We ----
    gemm_mfma<<<dim3(2048 / 128, DIV_UP(N, 128)), blk, 0, stream>>>(xbf, wt1, xlr1, N, 2048, 64);
    attn_hase<1024, 256, 512, 2, true><<<2560, blk, 0, stream>>>(
        xlr1, ea, We1, att1, edges, off, b1, h1, N);

    // ---- Layer 2: H=4, C=64, D=256 — 1 wave/node, CPL=4, G=16, NE=4, fp16 We ----
    gemm_mfma<<<dim3(512 / 128, DIV_UP(N, 128)), blk, 0, stream>>>(h1, wt2, xlr2, N, 512, 1024);
    attn_hase<256, 64, 256, 1, true><<<1280, blk, 0, stream>>>(
        xlr2, ea, We2, att2, edges, off, b2, h2, N);

    // ---- Layer 3: H=6, C=64, D=384 — 1 wave/node, CPL=8, 48 lanes, G=8, fp32 out ----
    gemm_mfma<<<dim3(768 / 128, DIV_UP(N, 128)), blk, 0, stream>>>(h2, wt3, xlr3, N, 768, 256);
    attn_noe1<384, 64, 8, false><<<DIV_UP(N, 4), blk, 0, stream>>>(
        xlr3, attp, edges3, off3, bp, h3, N);

    // ---- head ----
    mlp_kernel<<<G, 64, 0, stream>>>(h3, nn, Wfc1, bfc1, Wfc2, bfc2, (float*)d_out, G);
}

// Round 13
// 424.697 us; speedup vs baseline: 1.0169x; 1.0169x over previous
//
#include <hip/hip_runtime.h>
#include <hip/hip_bf16.h>

#define DIV_UP(a,b) (((a)+(b)-1)/(b))

typedef __attribute__((ext_vector_type(8))) short short8;
typedef __attribute__((ext_vector_type(4))) float floatx4;

// ---------- bf16 helpers (manual, deterministic RNE) ----------
static __device__ __forceinline__ unsigned short f2bf(float v) {
    unsigned u = __builtin_bit_cast(unsigned, v);
    u += 0x7fffu + ((u >> 16) & 1u);
    return (unsigned short)(u >> 16);
}
static __device__ __forceinline__ float bflo(unsigned v) {
    return __builtin_bit_cast(float, v << 16);
}
static __device__ __forceinline__ float bfhi(unsigned v) {
    return __builtin_bit_cast(float, v & 0xffff0000u);
}

template <int CPL>
static __device__ __forceinline__ void load_bf16v(const unsigned short* p, float* d) {
    if constexpr (CPL == 8) {
        uint4 v = *(const uint4*)p;
        d[0] = bflo(v.x); d[1] = bfhi(v.x);
        d[2] = bflo(v.y); d[3] = bfhi(v.y);
        d[4] = bflo(v.z); d[5] = bfhi(v.z);
        d[6] = bflo(v.w); d[7] = bfhi(v.w);
    } else if constexpr (CPL == 4) {
        uint2 v = *(const uint2*)p;
        d[0] = bflo(v.x); d[1] = bfhi(v.x);
        d[2] = bflo(v.y); d[3] = bfhi(v.y);
    } else if constexpr (CPL == 2) {
        unsigned v = *(const unsigned*)p;
        d[0] = bflo(v); d[1] = bfhi(v);
    } else {
        d[0] = bflo(*p);
    }
}

template <int CPL>
static __device__ __forceinline__ void store_bf16v(unsigned short* p, const float* s) {
    unsigned short tmp[CPL];
#pragma unroll
    for (int c = 0; c < CPL; ++c) tmp[c] = f2bf(s[c]);
    if constexpr (CPL == 8) *(uint4*)p = *(uint4*)tmp;
    else if constexpr (CPL == 4) *(ushort4*)p = *(ushort4*)tmp;
    else if constexpr (CPL == 2) *(ushort2*)p = *(ushort2*)tmp;
    else p[0] = tmp[0];
}

// ---------- DPP group reduction (VALU pipe, not DS) ----------
template <int CTRL>
static __device__ __forceinline__ float dpp_mv(float x) {
    int r = __builtin_amdgcn_update_dpp(0, __builtin_bit_cast(int, x), CTRL, 0xF, 0xF, false);
    return __builtin_bit_cast(float, r);
}
template <int G>
static __device__ __forceinline__ float group_reduce(float x) {
    x += dpp_mv<0xB1>(x);   // xor 1
    x += dpp_mv<0x4E>(x);   // xor 2 -> quad sums
    if constexpr (G == 8) {
        x += __shfl_xor(x, 4, 64);
    } else if constexpr (G >= 16) {
        x += dpp_mv<0x124>(x);  // row_ror:4
        x += dpp_mv<0x128>(x);  // row_ror:8 -> 16-lane sum
        if constexpr (G >= 32) x += __shfl_xor(x, 16, 64);
        if constexpr (G >= 64) x += __shfl_xor(x, 32, 64);
    }
    return x;
}

// ---------- merged weight prep: 3 transposed pairs + x->bf16 ----------
static __device__ __forceinline__ void tr_pair(const float* Wa, const float* Wb, int K, int Nn,
                                               unsigned short* Wt, int i) {
    int tot = K * Nn;
    const float* W = (i < tot) ? Wa : Wb;
    unsigned short* dst = Wt + ((i < tot) ? 0 : (size_t)Nn * K);
    int ii = (i < tot) ? i : i - tot;
    int k = ii % K, n = ii / K;
    dst[(size_t)n * K + k] = f2bf(W[(size_t)k * Nn + n]);
}

__global__ void prep_all(const float* __restrict__ x,
                         const float* __restrict__ Wl1, const float* __restrict__ Wr1,
                         const float* __restrict__ Wl2, const float* __restrict__ Wr2,
                         const float* __restrict__ Wlp, const float* __restrict__ Wrp,
                         unsigned short* __restrict__ xbf,
                         unsigned short* __restrict__ wt1, unsigned short* __restrict__ wt2,
                         unsigned short* __restrict__ wt3, int N) {
    const int S1 = 2 * 64 * 1024, S2 = 2 * 1024 * 256, S3 = 2 * 256 * 384;
    int id = blockIdx.x * blockDim.x + threadIdx.x;
    if (id < S1) tr_pair(Wl1, Wr1, 64, 1024, wt1, id);
    else if (id < S1 + S2) tr_pair(Wl2, Wr2, 1024, 256, wt2, id - S1);
    else if (id < S1 + S2 + S3) tr_pair(Wlp, Wrp, 256, 384, wt3, id - S1 - S2);
    else {
        int i = id - S1 - S2 - S3;
        if (i < N * 64) xbf[i] = f2bf(x[i]);
    }
}

// ---------- MFMA bf16 GEMM: C[M,Ntot] = A[M,K] @ Bt[Ntot,K]^T ----------
__global__ __launch_bounds__(256) void gemm_mfma(
    const unsigned short* __restrict__ A, const unsigned short* __restrict__ Bt,
    unsigned short* __restrict__ C, int M, int Ntot, int K) {
    constexpr int LDA = 40;
    __shared__ unsigned short As[128 * LDA];
    __shared__ unsigned short Bs[128 * LDA];
    const int tid = threadIdx.x;
    const int m0 = blockIdx.y * 128, n0 = blockIdx.x * 128;
    const int wave = tid >> 6, lane = tid & 63;
    const int wm = (wave >> 1) * 64, wn = (wave & 1) * 64;
    const int r15 = lane & 15, quad = lane >> 4;
    const int sr = tid >> 1, skc = tid & 1;
    floatx4 acc[4][4];
#pragma unroll
    for (int i = 0; i < 4; ++i)
#pragma unroll
        for (int j = 0; j < 4; ++j) acc[i][j] = (floatx4)0.f;

    for (int k0 = 0; k0 < K; k0 += 32) {
        uint4 a0 = make_uint4(0, 0, 0, 0), a1 = make_uint4(0, 0, 0, 0);
        int am = m0 + sr;
        if (am < M) {
            const unsigned short* ap = A + (size_t)am * K + k0 + skc * 16;
            a0 = *(const uint4*)ap;
            a1 = *(const uint4*)(ap + 8);
        }
        const unsigned short* bp = Bt + (size_t)(n0 + sr) * K + k0 + skc * 16;
        uint4 b0 = *(const uint4*)bp;
        uint4 b1 = *(const uint4*)(bp + 8);
        *(uint4*)(&As[sr * LDA + skc * 16]) = a0;
        *(uint4*)(&As[sr * LDA + skc * 16 + 8]) = a1;
        *(uint4*)(&Bs[sr * LDA + skc * 16]) = b0;
        *(uint4*)(&Bs[sr * LDA + skc * 16 + 8]) = b1;
        __syncthreads();
        short8 af[4], bfr[4];
#pragma unroll
        for (int i = 0; i < 4; ++i)
            af[i] = *(const short8*)(&As[(wm + i * 16 + r15) * LDA + quad * 8]);
#pragma unroll
        for (int j = 0; j < 4; ++j)
            bfr[j] = *(const short8*)(&Bs[(wn + j * 16 + r15) * LDA + quad * 8]);
#pragma unroll
        for (int i = 0; i < 4; ++i)
#pragma unroll
            for (int j = 0; j < 4; ++j)
                acc[i][j] = __builtin_amdgcn_mfma_f32_16x16x32_bf16(af[i], bfr[j], acc[i][j], 0, 0, 0);
        __syncthreads();
    }
#pragma unroll
    for (int i = 0; i < 4; ++i)
#pragma unroll
        for (int j = 0; j < 4; ++j)
#pragma unroll
            for (int r = 0; r < 4; ++r) {
                int m = m0 + wm + i * 16 + quad * 4 + r;
                int n = n0 + wn + j * 16 + r15;
                if (m < M) C[(size_t)m * Ntot + n] = f2bf(acc[i][j][r]);
            }
}

// ---------- CSR build for BOTH graphs ----------
__global__ void count2_kernel(const int* __restrict__ dst0, const int* __restrict__ dst1,
                              int E, int N, int* __restrict__ cnt) {
    int e = blockIdx.x * blockDim.x + threadIdx.x;
    if (e < E) atomicAdd(&cnt[dst0[e]], 1);
    else if (e < 2 * E) atomicAdd(&cnt[N + dst1[e - E]], 1);
}

__global__ __launch_bounds__(1024) void scan_kernel(const int* __restrict__ cnt_all, int N,
                                                    int* __restrict__ off_all, int* __restrict__ cur_all) {
    const int* cnt = cnt_all + blockIdx.x * N;
    int* off = off_all + blockIdx.x * (N + 1);
    int* cur = cur_all + blockIdx.x * N;
    __shared__ int part[1024];
    int t = threadIdx.x;
    int per = (N + 1023) >> 10;
    int base = t * per;
    int s = 0;
    for (int i = 0; i < per; ++i) { int idx = base + i; if (idx < N) s += cnt[idx]; }
    part[t] = s;
    __syncthreads();
    for (int d2 = 1; d2 < 1024; d2 <<= 1) {
        int v = (t >= d2) ? part[t - d2] : 0;
        __syncthreads();
        part[t] += v;
        __syncthreads();
    }
    int pre = (t == 0) ? 0 : part[t - 1];
    for (int i = 0; i < per; ++i) {
        int idx = base + i;
        if (idx < N) { off[idx] = pre; cur[idx] = pre; pre += cnt[idx]; }
    }
    if (t == 1023) off[N] = part[1023];
}

__global__ void fill2_kernel(const int* __restrict__ src0, const int* __restrict__ dst0,
                             const int* __restrict__ src1, const int* __restrict__ dst1,
                             int E, int N, int* __restrict__ cur, int2* __restrict__ edges) {
    int e = blockIdx.x * blockDim.x + threadIdx.x;
    if (e < E) {
        int p = atomicAdd(&cur[dst0[e]], 1);
        edges[p] = make_int2(src0[e], e);
    } else if (e < 2 * E) {
        int i = e - E;
        int p = atomicAdd(&cur[N + dst1[i]], 1);
        edges[E + p] = make_int2(src1[i], i);
    }
}

// ---------- fused attention (HASE): swizzled fp32 We in LDS, NE-edge groups, scalar edge meta ----------
template <int D, int CPL, int QP, int G, int NE>
static __device__ __forceinline__ void hase_group(
    const unsigned short* __restrict__ xlr, const float* __restrict__ ea,
    const float* wb, const float (&att_r)[CPL], const float (&xr_r)[CPL],
    const int2* ep /*uniform*/, int c0,
    float& m, float& l, float (&acc)[CPL]) {
    int2 e[NE];
#pragma unroll
    for (int n = 0; n < NE; ++n) e[n] = ep[n];
    float ev[NE][8];
#pragma unroll
    for (int n = 0; n < NE; ++n) {
        float4 a = ((const float4*)(ea + (size_t)e[n].y * 8))[0];
        float4 b = ((const float4*)(ea + (size_t)e[n].y * 8))[1];
        ev[n][0] = a.x; ev[n][1] = a.y; ev[n][2] = a.z; ev[n][3] = a.w;
        ev[n][4] = b.x; ev[n][5] = b.y; ev[n][6] = b.z; ev[n][7] = b.w;
    }
    float xv[NE][CPL], z[NE][CPL];
#pragma unroll
    for (int n = 0; n < NE; ++n) {
        load_bf16v<CPL>(xlr + (size_t)e[n].x * (2 * D) + c0, xv[n]);
#pragma unroll
        for (int c = 0; c < CPL; ++c) z[n][c] = xv[n][c] + xr_r[c];
    }
#pragma unroll
    for (int k = 0; k < 8; ++k) {
#pragma unroll
        for (int q = 0; q < CPL / 4; ++q) {
            float4 w4 = *(const float4*)(wb + k * D + q * QP);
#pragma unroll
            for (int n = 0; n < NE; ++n) {
                z[n][q * 4 + 0] = fmaf(ev[n][k], w4.x, z[n][q * 4 + 0]);
                z[n][q * 4 + 1] = fmaf(ev[n][k], w4.y, z[n][q * 4 + 1]);
                z[n][q * 4 + 2] = fmaf(ev[n][k], w4.z, z[n][q * 4 + 2]);
                z[n][q * 4 + 3] = fmaf(ev[n][k], w4.w, z[n][q * 4 + 3]);
            }
        }
    }
    float lg[NE];
#pragma unroll
    for (int n = 0; n < NE; ++n) {
        lg[n] = 0.f;
#pragma unroll
        for (int c = 0; c < CPL; ++c) {
            float a = z[n][c] > 0.f ? z[n][c] : 0.2f * z[n][c];
            lg[n] = fmaf(att_r[c], a, lg[n]);
        }
        lg[n] = group_reduce<G>(lg[n]);
    }
    float mn = m;
#pragma unroll
    for (int n = 0; n < NE; ++n) mn = fmaxf(mn, lg[n]);
    float sc = __expf(m - mn);
    float p[NE], ps = 0.f;
#pragma unroll
    for (int n = 0; n < NE; ++n) { p[n] = __expf(lg[n] - mn); ps += p[n]; }
    m = mn;
    l = fmaf(l, sc, ps);
#pragma unroll
    for (int c = 0; c < CPL; ++c) {
        float t = p[0] * xv[0][c];
#pragma unroll
        for (int n = 1; n < NE; ++n) t = fmaf(p[n], xv[n][c], t);
        acc[c] = fmaf(acc[c], sc, t);
    }
}

template <int D, int C, int CB, int WPN, bool RELU>
__global__ __launch_bounds__(256) void attn_hase(
    const unsigned short* __restrict__ xlr, const float* __restrict__ ea,
    const float* __restrict__ We, const float* __restrict__ att,
    const int2* __restrict__ edges, const int* __restrict__ off,
    const float* __restrict__ bias, unsigned short* __restrict__ outp, int N) {
    constexpr int CPL = CB / 64;
    constexpr int HW = CB / C;
    constexpr int G = 64 / HW;
    constexpr int NPB = 4 / WPN;
    constexpr int QP = CB * 4 / CPL;
    __shared__ float wsh[8 * D];
    for (int f4 = threadIdx.x; f4 < 2 * D; f4 += 256) {
        int k = f4 / (D / 4);
        int c = (f4 - k * (D / 4)) * 4;
        int b = c / CB, cc = c - b * CB;
        int ln = cc / CPL, q = (cc % CPL) / 4;
        int dst = k * (D / 4) + (b * CB + q * QP + ln * 4) / 4;
        ((float4*)wsh)[dst] = ((const float4*)We)[f4];
    }
    __syncthreads();

    const int wid = threadIdx.x >> 6, lane = threadIdx.x & 63;
    const int wv = wid % WPN, wn = wid / WPN;
    const int c0 = wv * CB + lane * CPL;
    const float* wb = wsh + wv * CB + lane * 4;

    float att_r[CPL];
#pragma unroll
    for (int c = 0; c < CPL; ++c) att_r[c] = att[c0 + c];

    for (int node = blockIdx.x * NPB + wn; node < N; node += gridDim.x * NPB) {
        float xr_r[CPL];
        load_bf16v<CPL>(xlr + (size_t)node * (2 * D) + D + c0, xr_r);
        float m = -1e30f, l = 0.f, acc[CPL];
#pragma unroll
        for (int c = 0; c < CPL; ++c) acc[c] = 0.f;

        const int jb = __builtin_amdgcn_readfirstlane(off[node]);
        const int je = __builtin_amdgcn_readfirstlane(off[node + 1]);
        int j = jb;
        for (; j + 4 <= je; j += 4)
            hase_group<D, CPL, QP, G, 4>(xlr, ea, wb, att_r, xr_r, edges + j, c0, m, l, acc);
        for (; j < je; ++j)
            hase_group<D, CPL, QP, G, 1>(xlr, ea, wb, att_r, xr_r, edges + j, c0, m, l, acc);

        float inv = 1.f / (l + 1e-16f);
        float r[CPL];
#pragma unroll
        for (int c = 0; c < CPL; ++c) {
            r[c] = fmaf(acc[c], inv, bias[c0 + c]);
            if constexpr (RELU) r[c] = fmaxf(r[c], 0.f);
        }
        store_bf16v<CPL>(outp + (size_t)node * D + c0, r);
    }
}

// ---------- fused attention, no edge_attr (layer 3): scalar, NE groups ----------
template <int D, int CPL, int G, int NE>
static __device__ __forceinline__ void noe_group(
    const unsigned short* __restrict__ xlr,
    const float (&att_r)[CPL], const float (&xr_r)[CPL],
    const int2* ep /*uniform*/, int c0,
    float& m, float& l, float (&acc)[CPL]) {
    int2 e[NE];
#pragma unroll
    for (int n = 0; n < NE; ++n) e[n] = ep[n];
    float xv[NE][CPL], lg[NE];
#pragma unroll
    for (int n = 0; n < NE; ++n)
        load_bf16v<CPL>(xlr + (size_t)e[n].x * (2 * D) + c0, xv[n]);
#pragma unroll
    for (int n = 0; n < NE; ++n) {
        lg[n] = 0.f;
#pragma unroll
        for (int c = 0; c < CPL; ++c) {
            float z = xv[n][c] + xr_r[c];
            z = z > 0.f ? z : 0.2f * z;
            lg[n] = fmaf(att_r[c], z, lg[n]);
        }
        lg[n] = group_reduce<G>(lg[n]);
    }
    float mn = m;
#pragma unroll
    for (int n = 0; n < NE; ++n) mn = fmaxf(mn, lg[n]);
    float sc = __expf(m - mn);
    float p[NE], ps = 0.f;
#pragma unroll
    for (int n = 0; n < NE; ++n) { p[n] = __expf(lg[n] - mn); ps += p[n]; }
    m = mn;
    l = fmaf(l, sc, ps);
#pragma unroll
    for (int c = 0; c < CPL; ++c) {
        float t = p[0] * xv[0][c];
#pragma unroll
        for (int n = 1; n < NE; ++n) t = fmaf(p[n], xv[n][c], t);
        acc[c] = fmaf(acc[c], sc, t);
    }
}

// D=384, C=64, CPL=8: 48 active lanes, G=8, 1 wave/node, fp32 out.
template <int D, int C, int CPL, bool RELU>
__global__ __launch_bounds__(256) void attn_noe1(
    const unsigned short* __restrict__ xlr, const float* __restrict__ att,
    const int2* __restrict__ edges, const int* __restrict__ off,
    const float* __restrict__ bias, float* __restrict__ outp, int N) {
    constexpr int ACT = D / CPL;  // 48
    constexpr int G = C / CPL;    // 8
    const int wid = threadIdx.x >> 6, lane = threadIdx.x & 63;
    const int node = blockIdx.x * 4 + wid;
    if (node >= N || lane >= ACT) return;
    const int c0 = lane * CPL;

    float att_r[CPL], xr_r[CPL];
#pragma unroll
    for (int c = 0; c < CPL; ++c) att_r[c] = att[c0 + c];
    load_bf16v<CPL>(xlr + (size_t)node * (2 * D) + D + c0, xr_r);

    float m = -1e30f, l = 0.f, acc[CPL];
#pragma unroll
    for (int c = 0; c < CPL; ++c) acc[c] = 0.f;

    const int jb = __builtin_amdgcn_readfirstlane(off[node]);
    const int je = __builtin_amdgcn_readfirstlane(off[node + 1]);
    int j = jb;
    for (; j + 4 <= je; j += 4)
        noe_group<D, CPL, G, 4>(xlr, att_r, xr_r, edges + j, c0, m, l, acc);
    for (; j < je; ++j)
        noe_group<D, CPL, G, 1>(xlr, att_r, xr_r, edges + j, c0, m, l, acc);

    float inv = 1.f / (l + 1e-16f);
    float* out = outp + (size_t)node * D + c0;
    float tmp[CPL];
#pragma unroll
    for (int c = 0; c < CPL; ++c) {
        tmp[c] = fmaf(acc[c], inv, bias[c0 + c]);
        if constexpr (RELU) tmp[c] = fmaxf(tmp[c], 0.f);
    }
    *(float4*)out = make_float4(tmp[0], tmp[1], tmp[2], tmp[3]);
    *(float4*)(out + 4) = make_float4(tmp[4], tmp[5], tmp[6], tmp[7]);
}

// ---------- head: 2-layer MLP on master (last) node of each graph ----------
__global__ void mlp_kernel(const float* __restrict__ h3, const int* __restrict__ nn,
                           const float* __restrict__ Wfc1, const float* __restrict__ bfc1,
                           const float* __restrict__ Wfc2, const float* __restrict__ bfc2,
                           float* __restrict__ out, int G) {
    int g = blockIdx.x, t = threadIdx.x;  // 64 threads
    int s = 0;
    for (int k = 0; k <= g; ++k) s += nn[k];
    const float* row = h3 + (size_t)(s - 1) * 384;
    float z = bfc1[t];
    for (int k = 0; k < 384; ++k) z = fmaf(row[k], Wfc1[k * 64 + t], z);
    z = fmaxf(z, 0.f);
    float v = z * Wfc2[t];
#pragma unroll
    for (int o = 32; o; o >>= 1) v += __shfl_xor(v, o, 64);
    if (t == 0) out[g] = v + bfc2[0];
}

extern "C" void kernel_launch(void* const* d_in, const int* in_sizes, int n_in,
                              void* d_out, int out_size, void* d_ws, size_t ws_size,
                              hipStream_t stream) {
    const float* x    = (const float*)d_in[0];
    const float* ea   = (const float*)d_in[1];
    const float* Wl1  = (const float*)d_in[2];
    const float* Wr1  = (const float*)d_in[3];
    const float* We1  = (const float*)d_in[4];
    const float* att1 = (const float*)d_in[5];
    const float* b1   = (const float*)d_in[6];
    const float* Wl2  = (const float*)d_in[7];
    const float* Wr2  = (const float*)d_in[8];
    const float* We2  = (const float*)d_in[9];
    const float* att2 = (const float*)d_in[10];
    const float* b2   = (const float*)d_in[11];
    const float* Wlp  = (const float*)d_in[12];
    const float* Wrp  = (const float*)d_in[13];
    const float* attp = (const float*)d_in[14];
    const float* bp   = (const float*)d_in[15];
    const float* Wfc1 = (const float*)d_in[16];
    const float* bfc1 = (const float*)d_in[17];
    const float* Wfc2 = (const float*)d_in[18];
    const float* bfc2 = (const float*)d_in[19];
    const int* ei     = (const int*)d_in[20];
    const int* eim    = (const int*)d_in[21];
    const int* nn     = (const int*)d_in[22];

    const int N = in_sizes[0] / 64;   // 20000
    const int E = in_sizes[20] / 2;   // 160000
    const int G = in_sizes[22];       // 100
    const int* src1 = ei,  *dst1 = ei + E;
    const int* srcm = eim, *dstm = eim + E;

    // ---- workspace layout (~160 MB peak) ----
    char* w = (char*)d_ws;
    size_t o = 0;
    auto alloc = [&](size_t b) { size_t r = o; o += (b + 255) & ~(size_t)255; return r; };
    char* R1 = w + alloc((size_t)N * 2048 * 2);
    unsigned short* xlr1 = (unsigned short*)R1;
    unsigned short* xlr3 = (unsigned short*)R1;
    float* h3 = (float*)(R1 + (size_t)N * 768 * 2 + 256);
    unsigned short* h1   = (unsigned short*)(w + alloc((size_t)N * 1024 * 2));
    unsigned short* xlr2 = (unsigned short*)(w + alloc((size_t)N * 512 * 2));
    unsigned short* h2   = (unsigned short*)(w + alloc((size_t)N * 256 * 2));
    unsigned short* xbf  = (unsigned short*)(w + alloc((size_t)N * 64 * 2));
    unsigned short* wt1  = (unsigned short*)(w + alloc((size_t)2048 * 64 * 2));
    unsigned short* wt2  = (unsigned short*)(w + alloc((size_t)512 * 1024 * 2));
    unsigned short* wt3  = (unsigned short*)(w + alloc((size_t)768 * 256 * 2));
    int*  cnt   = (int*)(w + alloc((size_t)2 * N * 4));
    int*  off   = (int*)(w + alloc((size_t)2 * (N + 1) * 4));
    int*  cur   = (int*)(w + alloc((size_t)2 * N * 4));
    int2* edges = (int2*)(w + alloc((size_t)2 * E * 8 + 4096));
    (void)ws_size; (void)n_in; (void)out_size;

    dim3 blk(256);

    // ---- weight prep (single merged launch) ----
    {
        int tot = 2 * 64 * 1024 + 2 * 1024 * 256 + 2 * 256 * 384 + N * 64;
        prep_all<<<DIV_UP(tot, 256), blk, 0, stream>>>(x, Wl1, Wr1, Wl2, Wr2, Wlp, Wrp,
                                                       xbf, wt1, wt2, wt3, N);
    }

    // ---- CSR for both graphs ----
    hipMemsetAsync(cnt, 0, (size_t)2 * N * 4, stream);
    count2_kernel<<<DIV_UP(2 * E, 256), blk, 0, stream>>>(dst1, dstm, E, N, cnt);
    scan_kernel<<<2, 1024, 0, stream>>>(cnt, N, off, cur);
    fill2_kernel<<<DIV_UP(2 * E, 256), blk, 0, stream>>>(src1, dst1, srcm, dstm, E, N, cur, edges);
    const int* off3 = off + (N + 1);
    int2* edges3 = edges + E;

    // ---- Layer 1: H=4, C=256, D=1024 — 2 waves/node, CPL=8, G=32, NE=4 ----
    gemm_mfma<<<dim3(2048 / 128, DIV_UP(N, 128)), blk, 0, stream>>>(xbf, wt1, xlr1, N, 2048, 64);
    attn_hase<1024, 256, 512, 2, true><<<2560, blk, 0, stream>>>(
        xlr1, ea, We1, att1, edges, off, b1, h1, N);

    // ---- Layer 2: H=4, C=64, D=256 — 1 wave/node, CPL=4, G=16, NE=4 ----
    gemm_mfma<<<dim3(512 / 128, DIV_UP(N, 128)), blk, 0, stream>>>(h1, wt2, xlr2, N, 512, 1024);
    attn_hase<256, 64, 256, 1, true><<<1280, blk, 0, stream>>>(
        xlr2, ea, We2, att2, edges, off, b2, h2, N);

    // ---- Layer 3: H=6, C=64, D=384 — 1 wave/node, CPL=8, 48 lanes, G=8, fp32 out ----
    gemm_mfma<<<dim3(768 / 128, DIV_UP(N, 128)), blk, 0, stream>>>(h2, wt3, xlr3, N, 768, 256);
    attn_noe1<384, 64, 8, false><<<DIV_UP(N, 4), blk, 0, stream>>>(
        xlr3, attp, edges3, off3, bp, h3, N);

    // ---- head ----
    mlp_kernel<<<G, 64, 0, stream>>>(h3, nn, Wfc1, bfc1, Wfc2, bfc2, (float*)d_out, G);
}

// Round 14
// 424.610 us; speedup vs baseline: 1.0171x; 1.0002x over previous
//
#include <hip/hip_runtime.h>
#include <hip/hip_bf16.h>

#define DIV_UP(a,b) (((a)+(b)-1)/(b))

typedef __attribute__((ext_vector_type(8))) short short8;
typedef __attribute__((ext_vector_type(4))) float floatx4;

// ---------- bf16 helpers (manual, deterministic RNE) ----------
static __device__ __forceinline__ unsigned short f2bf(float v) {
    unsigned u = __builtin_bit_cast(unsigned, v);
    u += 0x7fffu + ((u >> 16) & 1u);
    return (unsigned short)(u >> 16);
}
static __device__ __forceinline__ float bflo(unsigned v) {
    return __builtin_bit_cast(float, v << 16);
}
static __device__ __forceinline__ float bfhi(unsigned v) {
    return __builtin_bit_cast(float, v & 0xffff0000u);
}

template <int CPL>
static __device__ __forceinline__ void load_bf16v(const unsigned short* p, float* d) {
    if constexpr (CPL == 8) {
        uint4 v = *(const uint4*)p;
        d[0] = bflo(v.x); d[1] = bfhi(v.x);
        d[2] = bflo(v.y); d[3] = bfhi(v.y);
        d[4] = bflo(v.z); d[5] = bfhi(v.z);
        d[6] = bflo(v.w); d[7] = bfhi(v.w);
    } else if constexpr (CPL == 4) {
        uint2 v = *(const uint2*)p;
        d[0] = bflo(v.x); d[1] = bfhi(v.x);
        d[2] = bflo(v.y); d[3] = bfhi(v.y);
    } else if constexpr (CPL == 2) {
        unsigned v = *(const unsigned*)p;
        d[0] = bflo(v); d[1] = bfhi(v);
    } else {
        d[0] = bflo(*p);
    }
}

template <int CPL>
static __device__ __forceinline__ void store_bf16v(unsigned short* p, const float* s) {
    unsigned short tmp[CPL];
#pragma unroll
    for (int c = 0; c < CPL; ++c) tmp[c] = f2bf(s[c]);
    if constexpr (CPL == 8) *(uint4*)p = *(uint4*)tmp;
    else if constexpr (CPL == 4) *(ushort4*)p = *(ushort4*)tmp;
    else if constexpr (CPL == 2) *(ushort2*)p = *(ushort2*)tmp;
    else p[0] = tmp[0];
}

// ---------- DPP group reduction (VALU pipe, not DS) ----------
template <int CTRL>
static __device__ __forceinline__ float dpp_mv(float x) {
    int r = __builtin_amdgcn_update_dpp(0, __builtin_bit_cast(int, x), CTRL, 0xF, 0xF, false);
    return __builtin_bit_cast(float, r);
}
template <int G>
static __device__ __forceinline__ float group_reduce(float x) {
    x += dpp_mv<0xB1>(x);   // xor 1
    x += dpp_mv<0x4E>(x);   // xor 2 -> quad sums
    if constexpr (G == 8) {
        x += __shfl_xor(x, 4, 64);
    } else if constexpr (G >= 16) {
        x += dpp_mv<0x124>(x);  // row_ror:4
        x += dpp_mv<0x128>(x);  // row_ror:8 -> 16-lane sum
        if constexpr (G >= 32) x += __shfl_xor(x, 16, 64);
        if constexpr (G >= 64) x += __shfl_xor(x, 32, 64);
    }
    return x;
}

// ---------- merged weight prep: 3 transposed pairs + x->bf16 ----------
static __device__ __forceinline__ void tr_pair(const float* Wa, const float* Wb, int K, int Nn,
                                               unsigned short* Wt, int i) {
    int tot = K * Nn;
    const float* W = (i < tot) ? Wa : Wb;
    unsigned short* dst = Wt + ((i < tot) ? 0 : (size_t)Nn * K);
    int ii = (i < tot) ? i : i - tot;
    int k = ii % K, n = ii / K;
    dst[(size_t)n * K + k] = f2bf(W[(size_t)k * Nn + n]);
}

__global__ void prep_all(const float* __restrict__ x,
                         const float* __restrict__ Wl1, const float* __restrict__ Wr1,
                         const float* __restrict__ Wl2, const float* __restrict__ Wr2,
                         const float* __restrict__ Wlp, const float* __restrict__ Wrp,
                         unsigned short* __restrict__ xbf,
                         unsigned short* __restrict__ wt1, unsigned short* __restrict__ wt2,
                         unsigned short* __restrict__ wt3, int N) {
    const int S1 = 2 * 64 * 1024, S2 = 2 * 1024 * 256, S3 = 2 * 256 * 384;
    int id = blockIdx.x * blockDim.x + threadIdx.x;
    if (id < S1) tr_pair(Wl1, Wr1, 64, 1024, wt1, id);
    else if (id < S1 + S2) tr_pair(Wl2, Wr2, 1024, 256, wt2, id - S1);
    else if (id < S1 + S2 + S3) tr_pair(Wlp, Wrp, 256, 384, wt3, id - S1 - S2);
    else {
        int i = id - S1 - S2 - S3;
        if (i < N * 64) xbf[i] = f2bf(x[i]);
    }
}

// ---------- async global->LDS (16B per lane, dest = wave base + lane*16) ----------
static __device__ __forceinline__ void async16(const unsigned short* g, unsigned short* l) {
    __builtin_amdgcn_global_load_lds(
        (__attribute__((address_space(1))) void*)(void*)g,
        (__attribute__((address_space(3))) void*)l,
        16, 0, 0);
}

// ---------- MFMA bf16 GEMM: C[M,Ntot] = A[M,K] @ Bt[Ntot,K]^T ----------
// 128x128 tile, BK=32, unpadded [row][k] LDS (64B rows), global_load_lds staging.
// A-tile rows clamped to M-1 (dup rows only affect unstored C rows).
__global__ __launch_bounds__(256) void gemm_mfma(
    const unsigned short* __restrict__ A, const unsigned short* __restrict__ Bt,
    unsigned short* __restrict__ C, int M, int Ntot, int K) {
    __shared__ unsigned short As[128 * 32];
    __shared__ unsigned short Bs[128 * 32];
    const int tid = threadIdx.x;
    const int m0 = blockIdx.y * 128, n0 = blockIdx.x * 128;
    const int wave = tid >> 6, lane = tid & 63;
    const int wm = (wave >> 1) * 64, wn = (wave & 1) * 64;
    const int r15 = lane & 15, quad = lane >> 4;
    // staging: wave handles chunks {wave, wave+4}; chunk = 16 rows x 64B = 1KB.
    // lane i -> row_in_chunk = i>>2, 16B k-slot = i&3  (matches lane*16 LDS order).
    const int ric = lane >> 2;
    const int kc8 = (lane & 3) * 8;
    const int c0 = wave, c1 = wave + 4;
    int ar0 = m0 + c0 * 16 + ric; if (ar0 >= M) ar0 = M - 1;
    int ar1 = m0 + c1 * 16 + ric; if (ar1 >= M) ar1 = M - 1;
    const unsigned short* a0p = A + (size_t)ar0 * K + kc8;
    const unsigned short* a1p = A + (size_t)ar1 * K + kc8;
    const unsigned short* b0p = Bt + (size_t)(n0 + c0 * 16 + ric) * K + kc8;
    const unsigned short* b1p = Bt + (size_t)(n0 + c1 * 16 + ric) * K + kc8;
    unsigned short* al0 = &As[c0 * 512];
    unsigned short* al1 = &As[c1 * 512];
    unsigned short* bl0 = &Bs[c0 * 512];
    unsigned short* bl1 = &Bs[c1 * 512];

    floatx4 acc[4][4];
#pragma unroll
    for (int i = 0; i < 4; ++i)
#pragma unroll
        for (int j = 0; j < 4; ++j) acc[i][j] = (floatx4)0.f;

    for (int k0 = 0; k0 < K; k0 += 32) {
        async16(a0p + k0, al0);
        async16(a1p + k0, al1);
        async16(b0p + k0, bl0);
        async16(b1p + k0, bl1);
        __syncthreads();  // drains vmcnt before reads
        short8 af[4], bfr[4];
#pragma unroll
        for (int i = 0; i < 4; ++i)
            af[i] = *(const short8*)(&As[(wm + i * 16 + r15) * 32 + quad * 8]);
#pragma unroll
        for (int j = 0; j < 4; ++j)
            bfr[j] = *(const short8*)(&Bs[(wn + j * 16 + r15) * 32 + quad * 8]);
#pragma unroll
        for (int i = 0; i < 4; ++i)
#pragma unroll
            for (int j = 0; j < 4; ++j)
                acc[i][j] = __builtin_amdgcn_mfma_f32_16x16x32_bf16(af[i], bfr[j], acc[i][j], 0, 0, 0);
        __syncthreads();
    }
#pragma unroll
    for (int i = 0; i < 4; ++i)
#pragma unroll
        for (int j = 0; j < 4; ++j)
#pragma unroll
            for (int r = 0; r < 4; ++r) {
                int m = m0 + wm + i * 16 + quad * 4 + r;
                int n = n0 + wn + j * 16 + r15;
                if (m < M) C[(size_t)m * Ntot + n] = f2bf(acc[i][j][r]);
            }
}

// ---------- CSR build for BOTH graphs ----------
__global__ void count2_kernel(const int* __restrict__ dst0, const int* __restrict__ dst1,
                              int E, int N, int* __restrict__ cnt) {
    int e = blockIdx.x * blockDim.x + threadIdx.x;
    if (e < E) atomicAdd(&cnt[dst0[e]], 1);
    else if (e < 2 * E) atomicAdd(&cnt[N + dst1[e - E]], 1);
}

__global__ __launch_bounds__(1024) void scan_kernel(const int* __restrict__ cnt_all, int N,
                                                    int* __restrict__ off_all, int* __restrict__ cur_all) {
    const int* cnt = cnt_all + blockIdx.x * N;
    int* off = off_all + blockIdx.x * (N + 1);
    int* cur = cur_all + blockIdx.x * N;
    __shared__ int part[1024];
    int t = threadIdx.x;
    int per = (N + 1023) >> 10;
    int base = t * per;
    int s = 0;
    for (int i = 0; i < per; ++i) { int idx = base + i; if (idx < N) s += cnt[idx]; }
    part[t] = s;
    __syncthreads();
    for (int d2 = 1; d2 < 1024; d2 <<= 1) {
        int v = (t >= d2) ? part[t - d2] : 0;
        __syncthreads();
        part[t] += v;
        __syncthreads();
    }
    int pre = (t == 0) ? 0 : part[t - 1];
    for (int i = 0; i < per; ++i) {
        int idx = base + i;
        if (idx < N) { off[idx] = pre; cur[idx] = pre; pre += cnt[idx]; }
    }
    if (t == 1023) off[N] = part[1023];
}

__global__ void fill2_kernel(const int* __restrict__ src0, const int* __restrict__ dst0,
                             const int* __restrict__ src1, const int* __restrict__ dst1,
                             int E, int N, int* __restrict__ cur, int2* __restrict__ edges) {
    int e = blockIdx.x * blockDim.x + threadIdx.x;
    if (e < E) {
        int p = atomicAdd(&cur[dst0[e]], 1);
        edges[p] = make_int2(src0[e], e);
    } else if (e < 2 * E) {
        int i = e - E;
        int p = atomicAdd(&cur[N + dst1[i]], 1);
        edges[E + p] = make_int2(src1[i], i);
    }
}

// ---------- fused attention (HASE): swizzled fp32 We in LDS, NE-edge groups, scalar edge meta ----------
template <int D, int CPL, int QP, int G, int NE>
static __device__ __forceinline__ void hase_group(
    const unsigned short* __restrict__ xlr, const float* __restrict__ ea,
    const float* wb, const float (&att_r)[CPL], const float (&xr_r)[CPL],
    const int2* ep /*uniform*/, int c0,
    float& m, float& l, float (&acc)[CPL]) {
    int2 e[NE];
#pragma unroll
    for (int n = 0; n < NE; ++n) e[n] = ep[n];
    float ev[NE][8];
#pragma unroll
    for (int n = 0; n < NE; ++n) {
        float4 a = ((const float4*)(ea + (size_t)e[n].y * 8))[0];
        float4 b = ((const float4*)(ea + (size_t)e[n].y * 8))[1];
        ev[n][0] = a.x; ev[n][1] = a.y; ev[n][2] = a.z; ev[n][3] = a.w;
        ev[n][4] = b.x; ev[n][5] = b.y; ev[n][6] = b.z; ev[n][7] = b.w;
    }
    float xv[NE][CPL], z[NE][CPL];
#pragma unroll
    for (int n = 0; n < NE; ++n) {
        load_bf16v<CPL>(xlr + (size_t)e[n].x * (2 * D) + c0, xv[n]);
#pragma unroll
        for (int c = 0; c < CPL; ++c) z[n][c] = xv[n][c] + xr_r[c];
    }
#pragma unroll
    for (int k = 0; k < 8; ++k) {
#pragma unroll
        for (int q = 0; q < CPL / 4; ++q) {
            float4 w4 = *(const float4*)(wb + k * D + q * QP);
#pragma unroll
            for (int n = 0; n < NE; ++n) {
                z[n][q * 4 + 0] = fmaf(ev[n][k], w4.x, z[n][q * 4 + 0]);
                z[n][q * 4 + 1] = fmaf(ev[n][k], w4.y, z[n][q * 4 + 1]);
                z[n][q * 4 + 2] = fmaf(ev[n][k], w4.z, z[n][q * 4 + 2]);
                z[n][q * 4 + 3] = fmaf(ev[n][k], w4.w, z[n][q * 4 + 3]);
            }
        }
    }
    float lg[NE];
#pragma unroll
    for (int n = 0; n < NE; ++n) {
        lg[n] = 0.f;
#pragma unroll
        for (int c = 0; c < CPL; ++c) {
            float a = z[n][c] > 0.f ? z[n][c] : 0.2f * z[n][c];
            lg[n] = fmaf(att_r[c], a, lg[n]);
        }
        lg[n] = group_reduce<G>(lg[n]);
    }
    float mn = m;
#pragma unroll
    for (int n = 0; n < NE; ++n) mn = fmaxf(mn, lg[n]);
    float sc = __expf(m - mn);
    float p[NE], ps = 0.f;
#pragma unroll
    for (int n = 0; n < NE; ++n) { p[n] = __expf(lg[n] - mn); ps += p[n]; }
    m = mn;
    l = fmaf(l, sc, ps);
#pragma unroll
    for (int c = 0; c < CPL; ++c) {
        float t = p[0] * xv[0][c];
#pragma unroll
        for (int n = 1; n < NE; ++n) t = fmaf(p[n], xv[n][c], t);
        acc[c] = fmaf(acc[c], sc, t);
    }
}

template <int D, int C, int CB, int WPN, bool RELU>
__global__ __launch_bounds__(256) void attn_hase(
    const unsigned short* __restrict__ xlr, const float* __restrict__ ea,
    const float* __restrict__ We, const float* __restrict__ att,
    const int2* __restrict__ edges, const int* __restrict__ off,
    const float* __restrict__ bias, unsigned short* __restrict__ outp, int N) {
    constexpr int CPL = CB / 64;
    constexpr int HW = CB / C;
    constexpr int G = 64 / HW;
    constexpr int NPB = 4 / WPN;
    constexpr int QP = CB * 4 / CPL;
    __shared__ float wsh[8 * D];
    for (int f4 = threadIdx.x; f4 < 2 * D; f4 += 256) {
        int k = f4 / (D / 4);
        int c = (f4 - k * (D / 4)) * 4;
        int b = c / CB, cc = c - b * CB;
        int ln = cc / CPL, q = (cc % CPL) / 4;
        int dst = k * (D / 4) + (b * CB + q * QP + ln * 4) / 4;
        ((float4*)wsh)[dst] = ((const float4*)We)[f4];
    }
    __syncthreads();

    const int wid = threadIdx.x >> 6, lane = threadIdx.x & 63;
    const int wv = wid % WPN, wn = wid / WPN;
    const int c0 = wv * CB + lane * CPL;
    const float* wb = wsh + wv * CB + lane * 4;

    float att_r[CPL];
#pragma unroll
    for (int c = 0; c < CPL; ++c) att_r[c] = att[c0 + c];

    for (int node = blockIdx.x * NPB + wn; node < N; node += gridDim.x * NPB) {
        float xr_r[CPL];
        load_bf16v<CPL>(xlr + (size_t)node * (2 * D) + D + c0, xr_r);
        float m = -1e30f, l = 0.f, acc[CPL];
#pragma unroll
        for (int c = 0; c < CPL; ++c) acc[c] = 0.f;

        const int jb = __builtin_amdgcn_readfirstlane(off[node]);
        const int je = __builtin_amdgcn_readfirstlane(off[node + 1]);
        int j = jb;
        for (; j + 4 <= je; j += 4)
            hase_group<D, CPL, QP, G, 4>(xlr, ea, wb, att_r, xr_r, edges + j, c0, m, l, acc);
        for (; j < je; ++j)
            hase_group<D, CPL, QP, G, 1>(xlr, ea, wb, att_r, xr_r, edges + j, c0, m, l, acc);

        float inv = 1.f / (l + 1e-16f);
        float r[CPL];
#pragma unroll
        for (int c = 0; c < CPL; ++c) {
            r[c] = fmaf(acc[c], inv, bias[c0 + c]);
            if constexpr (RELU) r[c] = fmaxf(r[c], 0.f);
        }
        store_bf16v<CPL>(outp + (size_t)node * D + c0, r);
    }
}

// ---------- fused attention, no edge_attr (layer 3): scalar, NE groups ----------
template <int D, int CPL, int G, int NE>
static __device__ __forceinline__ void noe_group(
    const unsigned short* __restrict__ xlr,
    const float (&att_r)[CPL], const float (&xr_r)[CPL],
    const int2* ep /*uniform*/, int c0,
    float& m, float& l, float (&acc)[CPL]) {
    int2 e[NE];
#pragma unroll
    for (int n = 0; n < NE; ++n) e[n] = ep[n];
    float xv[NE][CPL], lg[NE];
#pragma unroll
    for (int n = 0; n < NE; ++n)
        load_bf16v<CPL>(xlr + (size_t)e[n].x * (2 * D) + c0, xv[n]);
#pragma unroll
    for (int n = 0; n < NE; ++n) {
        lg[n] = 0.f;
#pragma unroll
        for (int c = 0; c < CPL; ++c) {
            float z = xv[n][c] + xr_r[c];
            z = z > 0.f ? z : 0.2f * z;
            lg[n] = fmaf(att_r[c], z, lg[n]);
        }
        lg[n] = group_reduce<G>(lg[n]);
    }
    float mn = m;
#pragma unroll
    for (int n = 0; n < NE; ++n) mn = fmaxf(mn, lg[n]);
    float sc = __expf(m - mn);
    float p[NE], ps = 0.f;
#pragma unroll
    for (int n = 0; n < NE; ++n) { p[n] = __expf(lg[n] - mn); ps += p[n]; }
    m = mn;
    l = fmaf(l, sc, ps);
#pragma unroll
    for (int c = 0; c < CPL; ++c) {
        float t = p[0] * xv[0][c];
#pragma unroll
        for (int n = 1; n < NE; ++n) t = fmaf(p[n], xv[n][c], t);
        acc[c] = fmaf(acc[c], sc, t);
    }
}

// D=384, C=64, CPL=8: 48 active lanes, G=8, 1 wave/node, fp32 out.
template <int D, int C, int CPL, bool RELU>
__global__ __launch_bounds__(256) void attn_noe1(
    const unsigned short* __restrict__ xlr, const float* __restrict__ att,
    const int2* __restrict__ edges, const int* __restrict__ off,
    const float* __restrict__ bias, float* __restrict__ outp, int N) {
    constexpr int ACT = D / CPL;  // 48
    constexpr int G = C / CPL;    // 8
    const int wid = threadIdx.x >> 6, lane = threadIdx.x & 63;
    const int node = blockIdx.x * 4 + wid;
    if (node >= N || lane >= ACT) return;
    const int c0 = lane * CPL;

    float att_r[CPL], xr_r[CPL];
#pragma unroll
    for (int c = 0; c < CPL; ++c) att_r[c] = att[c0 + c];
    load_bf16v<CPL>(xlr + (size_t)node * (2 * D) + D + c0, xr_r);

    float m = -1e30f, l = 0.f, acc[CPL];
#pragma unroll
    for (int c = 0; c < CPL; ++c) acc[c] = 0.f;

    const int jb = __builtin_amdgcn_readfirstlane(off[node]);
    const int je = __builtin_amdgcn_readfirstlane(off[node + 1]);
    int j = jb;
    for (; j + 4 <= je; j += 4)
        noe_group<D, CPL, G, 4>(xlr, att_r, xr_r, edges + j, c0, m, l, acc);
    for (; j < je; ++j)
        noe_group<D, CPL, G, 1>(xlr, att_r, xr_r, edges + j, c0, m, l, acc);

    float inv = 1.f / (l + 1e-16f);
    float* out = outp + (size_t)node * D + c0;
    float tmp[CPL];
#pragma unroll
    for (int c = 0; c < CPL; ++c) {
        tmp[c] = fmaf(acc[c], inv, bias[c0 + c]);
        if constexpr (RELU) tmp[c] = fmaxf(tmp[c], 0.f);
    }
    *(float4*)out = make_float4(tmp[0], tmp[1], tmp[2], tmp[3]);
    *(float4*)(out + 4) = make_float4(tmp[4], tmp[5], tmp[6], tmp[7]);
}

// ---------- head: 2-layer MLP on master (last) node of each graph ----------
__global__ void mlp_kernel(const float* __restrict__ h3, const int* __restrict__ nn,
                           const float* __restrict__ Wfc1, const float* __restrict__ bfc1,
                           const float* __restrict__ Wfc2, const float* __restrict__ bfc2,
                           float* __restrict__ out, int G) {
    int g = blockIdx.x, t = threadIdx.x;  // 64 threads
    int s = 0;
    for (int k = 0; k <= g; ++k) s += nn[k];
    const float* row = h3 + (size_t)(s - 1) * 384;
    float z = bfc1[t];
    for (int k = 0; k < 384; ++k) z = fmaf(row[k], Wfc1[k * 64 + t], z);
    z = fmaxf(z, 0.f);
    float v = z * Wfc2[t];
#pragma unroll
    for (int o = 32; o; o >>= 1) v += __shfl_xor(v, o, 64);
    if (t == 0) out[g] = v + bfc2[0];
}

extern "C" void kernel_launch(void* const* d_in, const int* in_sizes, int n_in,
                              void* d_out, int out_size, void* d_ws, size_t ws_size,
                              hipStream_t stream) {
    const float* x    = (const float*)d_in[0];
    const float* ea   = (const float*)d_in[1];
    const float* Wl1  = (const float*)d_in[2];
    const float* Wr1  = (const float*)d_in[3];
    const float* We1  = (const float*)d_in[4];
    const float* att1 = (const float*)d_in[5];
    const float* b1   = (const float*)d_in[6];
    const float* Wl2  = (const float*)d_in[7];
    const float* Wr2  = (const float*)d_in[8];
    const float* We2  = (const float*)d_in[9];
    const float* att2 = (const float*)d_in[10];
    const float* b2   = (const float*)d_in[11];
    const float* Wlp  = (const float*)d_in[12];
    const float* Wrp  = (const float*)d_in[13];
    const float* attp = (const float*)d_in[14];
    const float* bp   = (const float*)d_in[15];
    const float* Wfc1 = (const float*)d_in[16];
    const float* bfc1 = (const float*)d_in[17];
    const float* Wfc2 = (const float*)d_in[18];
    const float* bfc2 = (const float*)d_in[19];
    const int* ei     = (const int*)d_in[20];
    const int* eim    = (const int*)d_in[21];
    const int* nn     = (const int*)d_in[22];

    const int N = in_sizes[0] / 64;   // 20000
    const int E = in_sizes[20] / 2;   // 160000
    const int G = in_sizes[22];       // 100
    const int* src1 = ei,  *dst1 = ei + E;
    const int* srcm = eim, *dstm = eim + E;

    // ---- workspace layout (~160 MB peak) ----
    char* w = (char*)d_ws;
    size_t o = 0;
    auto alloc = [&](size_t b) { size_t r = o; o += (b + 255) & ~(size_t)255; return r; };
    char* R1 = w + alloc((size_t)N * 2048 * 2);
    unsigned short* xlr1 = (unsigned short*)R1;
    unsigned short* xlr3 = (unsigned short*)R1;
    float* h3 = (float*)(R1 + (size_t)N * 768 * 2 + 256);
    unsigned short* h1   = (unsigned short*)(w + alloc((size_t)N * 1024 * 2));
    unsigned short* xlr2 = (unsigned short*)(w + alloc((size_t)N * 512 * 2));
    unsigned short* h2   = (unsigned short*)(w + alloc((size_t)N * 256 * 2));
    unsigned short* xbf  = (unsigned short*)(w + alloc((size_t)N * 64 * 2));
    unsigned short* wt1  = (unsigned short*)(w + alloc((size_t)2048 * 64 * 2));
    unsigned short* wt2  = (unsigned short*)(w + alloc((size_t)512 * 1024 * 2));
    unsigned short* wt3  = (unsigned short*)(w + alloc((size_t)768 * 256 * 2));
    int*  cnt   = (int*)(w + alloc((size_t)2 * N * 4));
    int*  off   = (int*)(w + alloc((size_t)2 * (N + 1) * 4));
    int*  cur   = (int*)(w + alloc((size_t)2 * N * 4));
    int2* edges = (int2*)(w + alloc((size_t)2 * E * 8 + 4096));
    (void)ws_size; (void)n_in; (void)out_size;

    dim3 blk(256);

    // ---- weight prep (single merged launch) ----
    {
        int tot = 2 * 64 * 1024 + 2 * 1024 * 256 + 2 * 256 * 384 + N * 64;
        prep_all<<<DIV_UP(tot, 256), blk, 0, stream>>>(x, Wl1, Wr1, Wl2, Wr2, Wlp, Wrp,
                                                       xbf, wt1, wt2, wt3, N);
    }

    // ---- CSR for both graphs ----
    hipMemsetAsync(cnt, 0, (size_t)2 * N * 4, stream);
    count2_kernel<<<DIV_UP(2 * E, 256), blk, 0, stream>>>(dst1, dstm, E, N, cnt);
    scan_kernel<<<2, 1024, 0, stream>>>(cnt, N, off, cur);
    fill2_kernel<<<DIV_UP(2 * E, 256), blk, 0, stream>>>(src1, dst1, srcm, dstm, E, N, cur, edges);
    const int* off3 = off + (N + 1);
    int2* edges3 = edges + E;

    // ---- Layer 1: H=4, C=256, D=1024 — 2 waves/node, CPL=8, G=32, NE=4 ----
    gemm_mfma<<<dim3(2048 / 128, DIV_UP(N, 128)), blk, 0, stream>>>(xbf, wt1, xlr1, N, 2048, 64);
    attn_hase<1024, 256, 512, 2, true><<<2560, blk, 0, stream>>>(
        xlr1, ea, We1, att1, edges, off, b1, h1, N);

    // ---- Layer 2: H=4, C=64, D=256 — 1 wave/node, CPL=4, G=16, NE=4 ----
    gemm_mfma<<<dim3(512 / 128, DIV_UP(N, 128)), blk, 0, stream>>>(h1, wt2, xlr2, N, 512, 1024);
    attn_hase<256, 64, 256, 1, true><<<1280, blk, 0, stream>>>(
        xlr2, ea, We2, att2, edges, off, b2, h2, N);

    // ---- Layer 3: H=6, C=64, D=384 — 1 wave/node, CPL=8, 48 lanes, G=8, fp32 out ----
    gemm_mfma<<<dim3(768 / 128, DIV_UP(N, 128)), blk, 0, stream>>>(h2, wt3, xlr3, N, 768, 256);
    attn_noe1<384, 64, 8, false><<<DIV_UP(N, 4), blk, 0, stream>>>(
        xlr3, attp, edges3, off3, bp, h3, N);

    // ---- head ----
    mlp_kernel<<<G, 64, 0, stream>>>(h3, nn, Wfc1, bfc1, Wfc2, bfc2, (float*)d_out, G);
}